// Round 4
// baseline (828.289 us; speedup 1.0000x reference)
//
#include <hip/hip_runtime.h>
#include <stdint.h>

#define B_    8
#define T_    4096
#define DIN   1024
#define HCH   1024
#define DOUT  1024
#define M_    (B_*T_)      // 32768 rows
#define CL    64           // scan chunk length
#define NCH   (T_/CL)      // 64 chunks

typedef unsigned short u16;
typedef unsigned int   u32;
typedef __attribute__((ext_vector_type(8))) __bf16 bf16x8;
typedef __attribute__((ext_vector_type(4))) float  f32x4;

static __device__ __forceinline__ u16 f2bf(float f){
  unsigned u = __builtin_bit_cast(unsigned, f);
  return (u16)((u + 0x7FFFu + ((u >> 16) & 1u)) >> 16);   // RNE
}
static __device__ __forceinline__ float bf2f(u16 h){
  return __builtin_bit_cast(float, ((unsigned)h) << 16);
}

#define GLOAD_LDS16(gp, lp) __builtin_amdgcn_global_load_lds( \
    (__attribute__((address_space(1))) void*)(gp),            \
    (__attribute__((address_space(3))) void*)(lp), 16, 0, 0)

#define BARRIER() do { __builtin_amdgcn_sched_barrier(0); \
                       __builtin_amdgcn_s_barrier();      \
                       __builtin_amdgcn_sched_barrier(0); } while(0)
#define WAIT_VM(n)  do { asm volatile("s_waitcnt vmcnt(" #n ")" ::: "memory"); \
                         __builtin_amdgcn_sched_barrier(0); } while(0)
#define WAIT_LGKM0() do { asm volatile("s_waitcnt lgkmcnt(0)" ::: "memory"); \
                          __builtin_amdgcn_sched_barrier(0); } while(0)

// ---------------- prep: W transposes (fp32->bf16, B^T layout) + is_init detect ----------------
static __device__ __forceinline__ void transpose_tile(const float* __restrict__ in,
                                                      u16* __restrict__ out,
                                                      int R, int C, int bx, int by){
  __shared__ float tile[32][33];
  int tx = threadIdx.x & 31, ty = threadIdx.x >> 5;   // 32 x 8
  int c0 = bx * 32, r0 = by * 32;
  #pragma unroll
  for (int j = 0; j < 4; ++j)
    tile[ty + j*8][tx] = in[(size_t)(r0 + ty + j*8) * C + c0 + tx];
  __syncthreads();
  #pragma unroll
  for (int j = 0; j < 4; ++j)
    out[(size_t)(c0 + ty + j*8) * R + r0 + tx] = f2bf(tile[tx][ty + j*8]);
}

__global__ void prep_kernel(const float* __restrict__ Whg, const float* __restrict__ Wout,
                            const u32* __restrict__ isin,
                            u16* __restrict__ WThg, u16* __restrict__ WTout,
                            int* __restrict__ flag){
  int bid = blockIdx.x;
  if (bid < 2048){                       // Whg: R=1024, C=2048 -> WThg [2048][1024]
    transpose_tile(Whg, WThg, DIN, 2*HCH, bid & 63, bid >> 6);
  } else if (bid < 3072){                // Wout: R=1024, C=1024 -> WTout [1024][1024]
    int b2 = bid - 2048;
    transpose_tile(Wout, WTout, HCH, DOUT, b2 & 31, b2 >> 5);
  } else {                               // detect: 1 => byte-flags, 0 => int32
    __shared__ int s;
    if (threadIdx.x == 0) s = 0;
    __syncthreads();
    int f = 0;
    for (int i = threadIdx.x; i < (B_*T_)/4; i += 256)
      if (isin[i] & 0xFFFFFF00u) f = 1;
    if (f) atomicOr(&s, 1);
    __syncthreads();
    if (threadIdx.x == 0) *flag = s;
  }
}

// ---------------- GEMM1: fused fp32->bf16 reg-staged A, 256^2, 3-barrier/tile ----------------
// X: [M][1024] fp32.  BT: WThg [2048][1024] bf16.  hg out: [M][2048] bf16.
__global__ __launch_bounds__(512, 2) void gemm1f_kernel(
    const float* __restrict__ X, const u16* __restrict__ BT, u16* __restrict__ hg)
{
  __shared__ u16 As[2][16384];   // [buf][256 rows][64 cols], XOR-swizzled granules
  __shared__ u16 Bs[2][16384];

  const int tid = threadIdx.x, lane = tid & 63, w = tid >> 6;
  const int wm = w >> 2, wn = w & 3;
  const int lr = lane & 15, lg = lane >> 4;
  const int l8 = lane >> 3, l7 = lane & 7;
  const int sgcol = (l7 ^ l8) * 8;             // pre-swizzled source granule (B path)

  const int nwg = gridDim.x;                   // 1024, %8==0
  const int wg  = ((int)blockIdx.x & 7) * (nwg >> 3) + ((int)blockIdx.x >> 3);
  const int mb  = wg & 127, nb = wg >> 7;
  const int m0  = mb * 256, n0 = nb * 256;

  const float* __restrict__ Xb = X  + (size_t)m0 * DIN;
  const u16*  __restrict__  Bb = BT + (size_t)n0 * DIN;

  // A reg-stage mapping: row = h*128 + (tid>>2), 16 consecutive floats at col (tid&3)*16
  const int ar = tid >> 2, ac = (tid & 3) * 16;

  float4 ra0[4], ra1[4];
  auto issA = [&](float4 (&ra)[4], int h, int t){
    const float* p = Xb + (size_t)(h*128 + ar) * DIN + t*64 + ac;
    #pragma unroll
    for (int i = 0; i < 4; ++i) ra[i] = ((const float4*)p)[i];
  };
  auto wrA = [&](float4 (&ra)[4], int h, int buf){
    int row = h*128 + ar;
    bf16x8 v0, v1;
    v0[0]=(__bf16)ra[0].x; v0[1]=(__bf16)ra[0].y; v0[2]=(__bf16)ra[0].z; v0[3]=(__bf16)ra[0].w;
    v0[4]=(__bf16)ra[1].x; v0[5]=(__bf16)ra[1].y; v0[6]=(__bf16)ra[1].z; v0[7]=(__bf16)ra[1].w;
    v1[0]=(__bf16)ra[2].x; v1[1]=(__bf16)ra[2].y; v1[2]=(__bf16)ra[2].z; v1[3]=(__bf16)ra[2].w;
    v1[4]=(__bf16)ra[3].x; v1[5]=(__bf16)ra[3].y; v1[6]=(__bf16)ra[3].z; v1[7]=(__bf16)ra[3].w;
    int s = row & 7, gb = (tid & 3) * 2;
    *(bf16x8*)&As[buf][row*64 + ((gb+0)^s)*8] = v0;
    *(bf16x8*)&As[buf][row*64 + ((gb+1)^s)*8] = v1;
  };
  auto stageB = [&](int buf, int t){
    #pragma unroll
    for (int half = 0; half < 2; ++half)
      #pragma unroll
      for (int i = 0; i < 2; ++i){
        int wi = w*2 + i;
        GLOAD_LDS16(Bb + (size_t)(half*128 + wi*8 + l8) * DIN + t*64 + sgcol,
                    &Bs[buf][half*8192 + wi*512]);
      }
  };

  bf16x8 af[4][2], b0[2][2], b1[2][2];
  f32x4 acc[2][2][4][2];
  #pragma unroll
  for (int a = 0; a < 2; ++a)
    #pragma unroll
    for (int b = 0; b < 2; ++b)
      #pragma unroll
      for (int m = 0; m < 4; ++m)
        #pragma unroll
        for (int n = 0; n < 2; ++n)
          acc[a][b][m][n] = (f32x4){0.f,0.f,0.f,0.f};

  auto ldA = [&](int buf, int mh){
    #pragma unroll
    for (int m = 0; m < 4; ++m)
      #pragma unroll
      for (int ks = 0; ks < 2; ++ks){
        int R = mh*128 + wm*64 + m*16 + lr;
        int g = (ks*4 + lg) ^ (lr & 7);
        af[m][ks] = *(const bf16x8*)&As[buf][R*64 + g*8];
      }
  };
  auto ldB = [&](bf16x8 (&bv)[2][2], int buf, int nh){
    #pragma unroll
    for (int n = 0; n < 2; ++n)
      #pragma unroll
      for (int ks = 0; ks < 2; ++ks){
        int R = nh*128 + wn*32 + n*16 + lr;
        int g = (ks*4 + lg) ^ (lr & 7);
        bv[n][ks] = *(const bf16x8*)&Bs[buf][R*64 + g*8];
      }
  };
  auto mmaQ = [&](f32x4 (&ac)[4][2], bf16x8 (&bv)[2][2]){
    __builtin_amdgcn_s_setprio(1);
    #pragma unroll
    for (int m = 0; m < 4; ++m)
      #pragma unroll
      for (int n = 0; n < 2; ++n)
        #pragma unroll
        for (int ks = 0; ks < 2; ++ks)
          ac[m][n] = __builtin_amdgcn_mfma_f32_16x16x32_bf16(af[m][ks], bv[n][ks], ac[m][n], 0, 0, 0);
    __builtin_amdgcn_s_setprio(0);
  };

  // ---- prologue: tile0 -> LDS[0]; tile1 loads held in regs / B(1) in flight ----
  issA(ra0, 0, 0); issA(ra1, 1, 0);   // FIFO: a0(0)[4] a1(0)[4]
  stageB(0, 0);                        //       B(0)[4]
  WAIT_VM(4);                          // a0(0), a1(0) landed
  wrA(ra0, 0, 0); wrA(ra1, 1, 0);
  issA(ra0, 0, 1); issA(ra1, 1, 1);    // a0(1) a1(1)
  stageB(1, 1);                        // B(1)
  WAIT_LGKM0();
  BARRIER();

  // ---- main loop t=0..13 (uniform ledger: vmcnt(8)/vmcnt(8)) ----
  for (int t = 0; t < 14; ++t){
    const int cur = t & 1, nxt = cur ^ 1;
    // P1: needs B(t) landed + a0(t+1) landed
    WAIT_VM(8);                        // drains B(t), a0(t+1)
    ldA(cur, 0); ldB(b0, cur, 0);
    wrA(ra0, 0, nxt);                  // A(t+1) h0 -> LDS
    issA(ra0, 0, t+2);                 // a0(t+2)
    WAIT_LGKM0();
    BARRIER();
    mmaQ(acc[0][0], b0);
    // P2: needs a1(t+1)
    WAIT_VM(8);                        // drains a1(t+1)
    ldB(b1, cur, 1);
    wrA(ra1, 1, nxt);
    issA(ra1, 1, t+2);                 // a1(t+2)
    WAIT_LGKM0();
    BARRIER();
    mmaQ(acc[0][1], b1);
    // P3
    ldA(cur, 1);
    stageB(cur, t+2);                  // B(t+2) -> Bs[cur] (reads of B(t) all behind P1/P2 barriers)
    WAIT_LGKM0();
    BARRIER();
    mmaQ(acc[1][1], b1);
    mmaQ(acc[1][0], b0);
  }
  // ---- t = 14 (cur=0): full drain, last writes ----
  {
    WAIT_VM(0);
    ldA(0, 0); ldB(b0, 0, 0); ldB(b1, 0, 1);
    wrA(ra0, 0, 1); wrA(ra1, 1, 1);
    WAIT_LGKM0();
    BARRIER();
    mmaQ(acc[0][0], b0); mmaQ(acc[0][1], b1);
    ldA(0, 1);
    mmaQ(acc[1][1], b1); mmaQ(acc[1][0], b0);
  }
  // ---- t = 15 (cur=1): pure compute ----
  {
    BARRIER();                         // ensure all waves' t=14 writes visible before reads
    ldA(1, 0); ldB(b0, 1, 0); ldB(b1, 1, 1);
    mmaQ(acc[0][0], b0); mmaQ(acc[0][1], b1);
    ldA(1, 1);
    mmaQ(acc[1][1], b1); mmaQ(acc[1][0], b0);
  }

  // ---- epilogue: write hg bf16 ----
  #pragma unroll
  for (int mh = 0; mh < 2; ++mh)
    #pragma unroll
    for (int nh = 0; nh < 2; ++nh)
      #pragma unroll
      for (int m = 0; m < 4; ++m)
        #pragma unroll
        for (int n = 0; n < 2; ++n)
          #pragma unroll
          for (int r = 0; r < 4; ++r){
            int row = m0 + mh*128 + wm*64 + m*16 + lg*4 + r;
            int col = n0 + nh*128 + wn*32 + n*16 + lr;
            hg[(size_t)row * 2048 + col] = f2bf(acc[mh][nh][m][n][r]);
          }
}

// ---------------- GEMM2: h @ W_out, bf16 in / fp32 out, 4-barrier/tile ----------------
__global__ __launch_bounds__(512, 2) void gemm2_kernel(
    const u16* __restrict__ A, const u16* __restrict__ BT, float* __restrict__ out)
{
  __shared__ u16 As[2][16384];
  __shared__ u16 Bs[2][16384];

  const int tid = threadIdx.x, lane = tid & 63, w = tid >> 6;
  const int wm = w >> 2, wn = w & 3;
  const int lr = lane & 15, lg = lane >> 4;
  const int l8 = lane >> 3, l7 = lane & 7;
  const int sgcol = (l7 ^ l8) * 8;

  const int nwg = gridDim.x;                  // 512, %8==0
  const int wg  = ((int)blockIdx.x & 7) * (nwg >> 3) + ((int)blockIdx.x >> 3);
  const int mb  = wg & 127, nb = wg >> 7;
  const int m0  = mb * 256, n0 = nb * 256;

  const u16* __restrict__ Ab = A  + (size_t)m0 * HCH;
  const u16* __restrict__ Bb = BT + (size_t)n0 * HCH;

  auto stage = [&](u16 (*S)[16384], int buf, int half, int tt, const u16* __restrict__ Gb){
    #pragma unroll
    for (int i = 0; i < 2; ++i){
      int wi = w*2 + i;
      GLOAD_LDS16(Gb + (size_t)(half*128 + wi*8 + l8) * HCH + tt*64 + sgcol,
                  &S[buf][half*8192 + wi*512]);
    }
  };

  bf16x8 af[4][2], b0[2][2], b1[2][2];
  f32x4 acc[2][2][4][2];
  #pragma unroll
  for (int a = 0; a < 2; ++a)
    #pragma unroll
    for (int b = 0; b < 2; ++b)
      #pragma unroll
      for (int m = 0; m < 4; ++m)
        #pragma unroll
        for (int n = 0; n < 2; ++n)
          acc[a][b][m][n] = (f32x4){0.f,0.f,0.f,0.f};

  auto ldA = [&](int buf, int mh){
    #pragma unroll
    for (int m = 0; m < 4; ++m)
      #pragma unroll
      for (int ks = 0; ks < 2; ++ks){
        int R = mh*128 + wm*64 + m*16 + lr;
        int g = (ks*4 + lg) ^ (lr & 7);
        af[m][ks] = *(const bf16x8*)&As[buf][R*64 + g*8];
      }
  };
  auto ldB = [&](bf16x8 (&bv)[2][2], int buf, int nh){
    #pragma unroll
    for (int n = 0; n < 2; ++n)
      #pragma unroll
      for (int ks = 0; ks < 2; ++ks){
        int R = nh*128 + wn*32 + n*16 + lr;
        int g = (ks*4 + lg) ^ (lr & 7);
        bv[n][ks] = *(const bf16x8*)&Bs[buf][R*64 + g*8];
      }
  };
  auto mmaQ = [&](f32x4 (&ac)[4][2], bf16x8 (&bv)[2][2]){
    __builtin_amdgcn_s_setprio(1);
    #pragma unroll
    for (int m = 0; m < 4; ++m)
      #pragma unroll
      for (int n = 0; n < 2; ++n)
        #pragma unroll
        for (int ks = 0; ks < 2; ++ks)
          ac[m][n] = __builtin_amdgcn_mfma_f32_16x16x32_bf16(af[m][ks], bv[n][ks], ac[m][n], 0, 0, 0);
    __builtin_amdgcn_s_setprio(0);
  };

  // prologue: tile0 fully, tile1 first 3 halves
  stage(As, 0, 0, 0, Ab); stage(Bs, 0, 0, 0, Bb);
  stage(Bs, 0, 1, 0, Bb); stage(As, 0, 1, 0, Ab);
  stage(As, 1, 0, 1, Ab); stage(Bs, 1, 0, 1, Bb); stage(Bs, 1, 1, 1, Bb);
  WAIT_VM(6);
  BARRIER();

  for (int t = 0; t < 16; ++t){
    const int cur = t & 1;
    // P1
    ldA(cur, 0); ldB(b0, cur, 0);
    if (t+1 < 16) stage(As, cur^1, 1, t+1, Ab);
    BARRIER();
    mmaQ(acc[0][0], b0);
    // P2
    ldB(b1, cur, 1);
    if (t+2 < 16) stage(As, cur, 0, t+2, Ab);
    BARRIER();
    mmaQ(acc[0][1], b1);
    // P3
    ldA(cur, 1);
    if (t+2 < 16) stage(Bs, cur, 0, t+2, Bb);
    BARRIER();
    mmaQ(acc[1][1], b1);
    // P4
    if (t+2 < 16) stage(Bs, cur, 1, t+2, Bb);
    if (t < 14)       { WAIT_VM(6); }
    else if (t == 14) { WAIT_VM(0); }
    BARRIER();
    mmaQ(acc[1][0], b0);
  }

  #pragma unroll
  for (int mh = 0; mh < 2; ++mh)
    #pragma unroll
    for (int nh = 0; nh < 2; ++nh)
      #pragma unroll
      for (int m = 0; m < 4; ++m)
        #pragma unroll
        for (int n = 0; n < 2; ++n)
          #pragma unroll
          for (int r = 0; r < 4; ++r){
            int row = m0 + mh*128 + wm*64 + m*16 + lg*4 + r;
            int col = n0 + nh*128 + wn*32 + n*16 + lr;
            out[(size_t)row * DOUT + col] = acc[mh][nh][m][n][r];
          }
}

// ---------------- fused elementwise: c = sigmoid(-g), v = sigmoid(g)*g_act(h) ----------------
static __device__ __forceinline__ void cv_from_hg(float hv, float gv, float& c, float& v){
  c = 1.f / (1.f + __expf(gv));
  float z = 1.f - c;
  float g = (hv >= 0.f) ? (hv + 0.5f) : (1.f / (1.f + __expf(-hv)));
  v = z * g;
}

// ---------------- chunked scan ----------------
__global__ void scanA_kernel(const u16* __restrict__ hg,
                             const void* __restrict__ isin, const int* __restrict__ mode,
                             float* __restrict__ Cc, float* __restrict__ Vc)
{
  int tid = blockIdx.x * 256 + threadIdx.x;
  int chp = tid & 511, b = (tid >> 9) & 7, ck = tid >> 12;
  int ch0 = chp * 2;
  int md = *mode;
  const unsigned char* ib = (const unsigned char*)isin;
  const int* ii = (const int*)isin;
  int t0 = b * T_ + ck * CL;
  float C0 = 1.f, V0 = 0.f, C1 = 1.f, V1 = 0.f;
  #pragma unroll 4
  for (int i = 0; i < CL; ++i){
    int t = t0 + i;
    const u16* rowp = hg + (size_t)t * 2048;
    u32 h2 = *(const u32*)(rowp + ch0);
    u32 g2 = *(const u32*)(rowp + 1024 + ch0);
    float hv0 = bf2f((u16)(h2 & 0xFFFF)), hv1 = bf2f((u16)(h2 >> 16));
    float gv0 = bf2f((u16)(g2 & 0xFFFF)), gv1 = bf2f((u16)(g2 >> 16));
    float c0, v0, c1, v1;
    cv_from_hg(hv0, gv0, c0, v0);
    cv_from_hg(hv1, gv1, c1, v1);
    int r = md ? (int)ib[t] : ii[t];
    if (r){ C0 = 0.f; V0 = v0; C1 = 0.f; V1 = v1; }
    else  { V0 = __fmaf_rn(c0, V0, v0); C0 *= c0;
            V1 = __fmaf_rn(c1, V1, v1); C1 *= c1; }
  }
  int o = ck * 8192 + b * 1024 + ch0;
  *(float2*)&Cc[o] = make_float2(C0, C1);
  *(float2*)&Vc[o] = make_float2(V0, V1);
}

__global__ void scanB_kernel(const float* __restrict__ Cc, const float* __restrict__ Vc,
                             float* __restrict__ hin)
{
  int idx = blockIdx.x * 256 + threadIdx.x;   // 0..8191
  float h = 0.f;
  #pragma unroll 8
  for (int ck = 0; ck < NCH; ++ck){
    int o = ck * 8192 + idx;
    hin[o] = h;
    h = __fmaf_rn(Cc[o], h, Vc[o]);
  }
}

__global__ void scanC_kernel(const u16* __restrict__ hg,
                             const void* __restrict__ isin, const int* __restrict__ mode,
                             const float* __restrict__ hin,
                             u16* __restrict__ hbf, float* __restrict__ hn)
{
  int tid = blockIdx.x * 256 + threadIdx.x;
  int chp = tid & 511, b = (tid >> 9) & 7, ck = tid >> 12;
  int ch0 = chp * 2;
  int md = *mode;
  const unsigned char* ib = (const unsigned char*)isin;
  const int* ii = (const int*)isin;
  int t0 = b * T_ + ck * CL;
  int o = ck * 8192 + b * 1024 + ch0;
  float h0 = hin[o], h1 = hin[o + 1];
  #pragma unroll 4
  for (int i = 0; i < CL; ++i){
    int t = t0 + i;
    const u16* rowp = hg + (size_t)t * 2048;
    u32 h2 = *(const u32*)(rowp + ch0);
    u32 g2 = *(const u32*)(rowp + 1024 + ch0);
    float hv0 = bf2f((u16)(h2 & 0xFFFF)), hv1 = bf2f((u16)(h2 >> 16));
    float gv0 = bf2f((u16)(g2 & 0xFFFF)), gv1 = bf2f((u16)(g2 >> 16));
    float c0, v0, c1, v1;
    cv_from_hg(hv0, gv0, c0, v0);
    cv_from_hg(hv1, gv1, c1, v1);
    int r = md ? (int)ib[t] : ii[t];
    h0 = r ? v0 : __fmaf_rn(c0, h0, v0);
    h1 = r ? v1 : __fmaf_rn(c1, h1, v1);
    *(u32*)&hbf[(size_t)t * HCH + ch0] = (u32)f2bf(h0) | ((u32)f2bf(h1) << 16);
  }
  if (ck == NCH - 1){ hn[b * 1024 + ch0] = h0; hn[b * 1024 + ch0 + 1] = h1; }
}

// ---------------- launcher ----------------
extern "C" void kernel_launch(void* const* d_in, const int* in_sizes, int n_in,
                              void* d_out, int out_size, void* d_ws, size_t ws_size,
                              hipStream_t stream)
{
  const float* x    = (const float*)d_in[0];
  const void*  isin = d_in[1];
  const float* Whg  = (const float*)d_in[2];
  const float* Wout = (const float*)d_in[3];
  float* out = (float*)d_out;

  char* ws = (char*)d_ws;
  size_t off = 0;
  auto alloc = [&](size_t bytes) -> char* {
    char* p = ws + off;
    off += (bytes + 255) & ~(size_t)255;
    return p;
  };
  u16*   WThg  = (u16*)  alloc((size_t)2 * HCH * DIN * 2);   // 4 MB
  u16*   WTout = (u16*)  alloc((size_t)DOUT * HCH * 2);      // 2 MB
  u16*   hg    = (u16*)  alloc((size_t)M_ * 2 * HCH * 2);    // 134 MB
  u16*   hbf   = (u16*)  alloc((size_t)M_ * HCH * 2);        // 67 MB
  float* Cc    = (float*)alloc((size_t)NCH * 8192 * 4);      // 2 MB
  float* Vc    = (float*)alloc((size_t)NCH * 8192 * 4);      // 2 MB
  float* hin   = (float*)alloc((size_t)NCH * 8192 * 4);      // 2 MB
  int*   mode  = (int*)  alloc(256);
  (void)ws_size; (void)in_sizes; (void)n_in; (void)out_size;

  prep_kernel<<<3073, 256, 0, stream>>>(Whg, Wout, (const u32*)isin, WThg, WTout, mode);
  gemm1f_kernel<<<1024, 512, 0, stream>>>(x, WThg, hg);
  scanA_kernel<<<(8192*NCH/2)/256, 256, 0, stream>>>(hg, isin, mode, Cc, Vc);
  scanB_kernel<<<8192/256, 256, 0, stream>>>(Cc, Vc, hin);
  scanC_kernel<<<(8192*NCH/2)/256, 256, 0, stream>>>(hg, isin, mode, hin, hbf,
                                                     out + (size_t)M_ * DOUT);
  gemm2_kernel<<<512, 512, 0, stream>>>(hbf, WTout, out);
}

// Round 7
// 613.151 us; speedup vs baseline: 1.3509x; 1.3509x over previous
//
#include <hip/hip_runtime.h>
#include <stdint.h>

#define B_    8
#define T_    4096
#define DIN   1024
#define HCH   1024
#define DOUT  1024
#define M_    (B_*T_)      // 32768 rows
#define CL    64           // scan chunk length
#define NCH   (T_/CL)      // 64 chunks

typedef unsigned short u16;
typedef unsigned int   u32;
typedef __attribute__((ext_vector_type(8))) __bf16 bf16x8;
typedef __attribute__((ext_vector_type(4))) float  f32x4;

static __device__ __forceinline__ u16 f2bf(float f){
  unsigned u = __builtin_bit_cast(unsigned, f);
  return (u16)((u + 0x7FFFu + ((u >> 16) & 1u)) >> 16);   // RNE
}
static __device__ __forceinline__ float bf2f(u16 h){
  return __builtin_bit_cast(float, ((unsigned)h) << 16);
}

#define GLOAD_LDS16(gp, lp) __builtin_amdgcn_global_load_lds( \
    (__attribute__((address_space(1))) void*)(gp),            \
    (__attribute__((address_space(3))) void*)(lp), 16, 0, 0)

#define BARRIER() do { __builtin_amdgcn_sched_barrier(0); \
                       __builtin_amdgcn_s_barrier();      \
                       __builtin_amdgcn_sched_barrier(0); } while(0)

// ---------------- prep: x->bf16 cvt + W transposes + is_init detect (1 dispatch) ----------------
static __device__ __forceinline__ void transpose_tile(const float* __restrict__ in,
                                                      u16* __restrict__ out,
                                                      int R, int C, int bx, int by){
  __shared__ float tile[32][33];
  int tx = threadIdx.x & 31, ty = threadIdx.x >> 5;   // 32 x 8
  int c0 = bx * 32, r0 = by * 32;
  #pragma unroll
  for (int j = 0; j < 4; ++j)
    tile[ty + j*8][tx] = in[(size_t)(r0 + ty + j*8) * C + c0 + tx];
  __syncthreads();
  #pragma unroll
  for (int j = 0; j < 4; ++j)
    out[(size_t)(c0 + ty + j*8) * R + r0 + tx] = f2bf(tile[tx][ty + j*8]);
}

__global__ void prep_kernel(const float* __restrict__ x, u16* __restrict__ xbf,
                            const float* __restrict__ Whg, const float* __restrict__ Wout,
                            const u32* __restrict__ isin,
                            u16* __restrict__ WThg, u16* __restrict__ WTout,
                            int* __restrict__ flag){
  int bid = blockIdx.x;
  if (bid < 2048){                       // Whg: [1024][2048] -> WThg [2048][1024]
    transpose_tile(Whg, WThg, DIN, 2*HCH, bid & 63, bid >> 6);
  } else if (bid < 3072){                // Wout: [1024][1024] -> WTout [1024][1024]
    int b2 = bid - 2048;
    transpose_tile(Wout, WTout, HCH, DOUT, b2 & 31, b2 >> 5);
  } else if (bid == 3072){               // detect: 1 => byte-flags, 0 => int32
    __shared__ int s;
    if (threadIdx.x == 0) s = 0;
    __syncthreads();
    int f = 0;
    for (int i = threadIdx.x; i < (B_*T_)/4; i += 256)
      if (isin[i] & 0xFFFFFF00u) f = 1;
    if (f) atomicOr(&s, 1);
    __syncthreads();
    if (threadIdx.x == 0) *flag = s;
  } else {                               // cvt: 8192 blocks x 256 thr x 4 float4
    int cb = bid - 3073;
    #pragma unroll
    for (int k = 0; k < 4; ++k){
      int i = (cb*4 + k)*256 + threadIdx.x;
      float4 v = ((const float4*)x)[i];
      ushort4 o;
      o.x = f2bf(v.x); o.y = f2bf(v.y); o.z = f2bf(v.z); o.w = f2bf(v.w);
      ((ushort4*)xbf)[i] = o;
    }
  }
}

// ---------------- 8-phase 256^2 GEMM (round-3 proven schedule, swapped-operand epilogue) ----
// A: [M][1024] bf16.  BT: [NOUT][1024] bf16 (B^T layout).  out: [M][NOUT].
// acc = mfma(b_frag, a_frag) => D=(A*B)^T fragment: lane(lg,lr) holds
// out_row = ...m*16+lr, out_cols = ...n*16+lg*4+{0..3}  -> packed row-major stores.
template<bool BF16OUT, int NOUT>
__global__ __launch_bounds__(512, 2) void gemm8p_kernel(
    const u16* __restrict__ A, const u16* __restrict__ BT, void* __restrict__ outv)
{
  __shared__ u16 As[2][16384];   // [buf][256 rows][64 cols], XOR-swizzled granules
  __shared__ u16 Bs[2][16384];

  const int tid = threadIdx.x, lane = tid & 63, w = tid >> 6;
  const int wm = w >> 2, wn = w & 3;
  const int lr = lane & 15, lg = lane >> 4;
  const int l8 = lane >> 3, l7 = lane & 7;
  const int sgcol = (l7 ^ l8) * 8;             // pre-swizzled source granule

  const int nwg = gridDim.x;                   // %8 == 0
  const int wg  = ((int)blockIdx.x & 7) * (nwg >> 3) + ((int)blockIdx.x >> 3);
  const int mb  = wg & 127, nb = wg >> 7;
  const int m0  = mb * 256, n0 = nb * 256;

  const u16* __restrict__ Ab = A  + (size_t)m0 * 1024;
  const u16* __restrict__ Bb = BT + (size_t)n0 * 1024;

  auto stage = [&](u16 (*S)[16384], int buf, int half, int tt, const u16* __restrict__ Gb){
    #pragma unroll
    for (int i = 0; i < 2; ++i){
      int wi = w*2 + i;                        // 1KB window 0..15 within half
      GLOAD_LDS16(Gb + (size_t)(half*128 + wi*8 + l8) * 1024 + tt*64 + sgcol,
                  &S[buf][half*8192 + wi*512]);
    }
  };

  bf16x8 af[4][2], b0[2][2], b1[2][2];
  f32x4 acc[2][2][4][2];
  #pragma unroll
  for (int a = 0; a < 2; ++a)
    #pragma unroll
    for (int b = 0; b < 2; ++b)
      #pragma unroll
      for (int m = 0; m < 4; ++m)
        #pragma unroll
        for (int n = 0; n < 2; ++n)
          acc[a][b][m][n] = (f32x4){0.f,0.f,0.f,0.f};

  auto ldA = [&](int buf, int mh){
    #pragma unroll
    for (int m = 0; m < 4; ++m)
      #pragma unroll
      for (int ks = 0; ks < 2; ++ks){
        int R = mh*128 + wm*64 + m*16 + lr;
        int g = (ks*4 + lg) ^ (lr & 7);
        af[m][ks] = *(const bf16x8*)&As[buf][R*64 + g*8];
      }
  };
  auto ldB = [&](bf16x8 (&bv)[2][2], int buf, int nh){
    #pragma unroll
    for (int n = 0; n < 2; ++n)
      #pragma unroll
      for (int ks = 0; ks < 2; ++ks){
        int R = nh*128 + wn*32 + n*16 + lr;
        int g = (ks*4 + lg) ^ (lr & 7);
        bv[n][ks] = *(const bf16x8*)&Bs[buf][R*64 + g*8];
      }
  };
  auto mmaQ = [&](f32x4 (&ac)[4][2], bf16x8 (&bv)[2][2]){
    __builtin_amdgcn_s_setprio(1);
    #pragma unroll
    for (int m = 0; m < 4; ++m)
      #pragma unroll
      for (int n = 0; n < 2; ++n)
        #pragma unroll
        for (int ks = 0; ks < 2; ++ks)   // SWAPPED operands: D = (A*B)^T fragments
          ac[m][n] = __builtin_amdgcn_mfma_f32_16x16x32_bf16(bv[n][ks], af[m][ks], ac[m][n], 0, 0, 0);
    __builtin_amdgcn_s_setprio(0);
  };

  // ---- prologue: tile0 all 4 halves, tile1 first 3 halves ----
  stage(As, 0, 0, 0, Ab);   // t0.Ah0
  stage(Bs, 0, 0, 0, Bb);   // t0.Bh0
  stage(Bs, 0, 1, 0, Bb);   // t0.Bh1
  stage(As, 0, 1, 0, Ab);   // t0.Ah1
  stage(As, 1, 0, 1, Ab);   // t1.Ah0
  stage(Bs, 1, 0, 1, Bb);   // t1.Bh0
  stage(Bs, 1, 1, 1, Bb);   // t1.Bh1
  asm volatile("s_waitcnt vmcnt(6)" ::: "memory");   // tile0 fully landed
  BARRIER();

  // ---- main loop: 16 K-tiles, 4 phases each (round-3 measured schedule) ----
  for (int t = 0; t < 16; ++t){
    int cur = t & 1;
    // P1 — quadrant (mh0, nh0); stage (t+1).Ah1
    ldA(cur, 0);
    ldB(b0, cur, 0);
    if (t+1 < 16) stage(As, cur^1, 1, t+1, Ab);
    BARRIER();
    mmaQ(acc[0][0], b0);
    BARRIER();
    // P2 — quadrant (mh0, nh1); stage (t+2).Ah0
    ldB(b1, cur, 1);
    if (t+2 < 16) stage(As, cur, 0, t+2, Ab);
    BARRIER();
    mmaQ(acc[0][1], b1);
    BARRIER();
    // P3 — quadrant (mh1, nh1); stage (t+2).Bh0
    ldA(cur, 1);
    if (t+2 < 16) stage(Bs, cur, 0, t+2, Bb);
    BARRIER();
    mmaQ(acc[1][1], b1);
    BARRIER();
    // P4 — quadrant (mh1, nh0); stage (t+2).Bh1; counted vmcnt
    if (t+2 < 16) stage(Bs, cur, 1, t+2, Bb);
    if (t < 14)       { asm volatile("s_waitcnt vmcnt(6)" ::: "memory"); }
    else if (t == 14) { asm volatile("s_waitcnt vmcnt(0)" ::: "memory"); }
    BARRIER();
    mmaQ(acc[1][0], b0);
    BARRIER();
  }

  // ---- epilogue: transposed fragments -> packed row-major stores ----
  #pragma unroll
  for (int mh = 0; mh < 2; ++mh)
    #pragma unroll
    for (int m = 0; m < 4; ++m){
      int row = m0 + mh*128 + wm*64 + m*16 + lr;
      #pragma unroll
      for (int nh = 0; nh < 2; ++nh)
        #pragma unroll
        for (int n = 0; n < 2; ++n){
          int col = n0 + nh*128 + wn*32 + n*16 + lg*4;
          f32x4 v = acc[mh][nh][m][n];
          if (BF16OUT){
            ushort4 p;
            p.x = f2bf(v[0]); p.y = f2bf(v[1]); p.z = f2bf(v[2]); p.w = f2bf(v[3]);
            *(ushort4*)&((u16*)outv)[(size_t)row * NOUT + col] = p;
          } else {
            float4 p = make_float4(v[0], v[1], v[2], v[3]);
            *(float4*)&((float*)outv)[(size_t)row * NOUT + col] = p;
          }
        }
    }
}

// ---------------- fused elementwise: c = sigmoid(-g), v = sigmoid(g)*g_act(h) ----------------
static __device__ __forceinline__ void cv_from_hg(float hv, float gv, float& c, float& v){
  c = 1.f / (1.f + __expf(gv));
  float z = 1.f - c;
  float g = (hv >= 0.f) ? (hv + 0.5f) : (1.f / (1.f + __expf(-hv)));
  v = z * g;
}

// ---------------- chunked scan ----------------
__global__ void scanA_kernel(const u16* __restrict__ hg,
                             const void* __restrict__ isin, const int* __restrict__ mode,
                             float* __restrict__ Cc, float* __restrict__ Vc)
{
  int tid = blockIdx.x * 256 + threadIdx.x;
  int chp = tid & 511, b = (tid >> 9) & 7, ck = tid >> 12;
  int ch0 = chp * 2;
  int md = *mode;
  const unsigned char* ib = (const unsigned char*)isin;
  const int* ii = (const int*)isin;
  int t0 = b * T_ + ck * CL;
  float C0 = 1.f, V0 = 0.f, C1 = 1.f, V1 = 0.f;
  #pragma unroll 4
  for (int i = 0; i < CL; ++i){
    int t = t0 + i;
    const u16* rowp = hg + (size_t)t * 2048;
    u32 h2 = *(const u32*)(rowp + ch0);
    u32 g2 = *(const u32*)(rowp + 1024 + ch0);
    float hv0 = bf2f((u16)(h2 & 0xFFFF)), hv1 = bf2f((u16)(h2 >> 16));
    float gv0 = bf2f((u16)(g2 & 0xFFFF)), gv1 = bf2f((u16)(g2 >> 16));
    float c0, v0, c1, v1;
    cv_from_hg(hv0, gv0, c0, v0);
    cv_from_hg(hv1, gv1, c1, v1);
    int r = md ? (int)ib[t] : ii[t];
    if (r){ C0 = 0.f; V0 = v0; C1 = 0.f; V1 = v1; }
    else  { V0 = __fmaf_rn(c0, V0, v0); C0 *= c0;
            V1 = __fmaf_rn(c1, V1, v1); C1 *= c1; }
  }
  int o = ck * 8192 + b * 1024 + ch0;
  *(float2*)&Cc[o] = make_float2(C0, C1);
  *(float2*)&Vc[o] = make_float2(V0, V1);
}

__global__ void scanB_kernel(const float* __restrict__ Cc, const float* __restrict__ Vc,
                             float* __restrict__ hin)
{
  int idx = blockIdx.x * 256 + threadIdx.x;   // 0..8191
  float h = 0.f;
  #pragma unroll 8
  for (int ck = 0; ck < NCH; ++ck){
    int o = ck * 8192 + idx;
    hin[o] = h;
    h = __fmaf_rn(Cc[o], h, Vc[o]);
  }
}

__global__ void scanC_kernel(const u16* __restrict__ hg,
                             const void* __restrict__ isin, const int* __restrict__ mode,
                             const float* __restrict__ hin,
                             u16* __restrict__ hbf, float* __restrict__ hn)
{
  int tid = blockIdx.x * 256 + threadIdx.x;
  int chp = tid & 511, b = (tid >> 9) & 7, ck = tid >> 12;
  int ch0 = chp * 2;
  int md = *mode;
  const unsigned char* ib = (const unsigned char*)isin;
  const int* ii = (const int*)isin;
  int t0 = b * T_ + ck * CL;
  int o = ck * 8192 + b * 1024 + ch0;
  float h0 = hin[o], h1 = hin[o + 1];
  #pragma unroll 4
  for (int i = 0; i < CL; ++i){
    int t = t0 + i;
    const u16* rowp = hg + (size_t)t * 2048;
    u32 h2 = *(const u32*)(rowp + ch0);
    u32 g2 = *(const u32*)(rowp + 1024 + ch0);
    float hv0 = bf2f((u16)(h2 & 0xFFFF)), hv1 = bf2f((u16)(h2 >> 16));
    float gv0 = bf2f((u16)(g2 & 0xFFFF)), gv1 = bf2f((u16)(g2 >> 16));
    float c0, v0, c1, v1;
    cv_from_hg(hv0, gv0, c0, v0);
    cv_from_hg(hv1, gv1, c1, v1);
    int r = md ? (int)ib[t] : ii[t];
    h0 = r ? v0 : __fmaf_rn(c0, h0, v0);
    h1 = r ? v1 : __fmaf_rn(c1, h1, v1);
    *(u32*)&hbf[(size_t)t * HCH + ch0] = (u32)f2bf(h0) | ((u32)f2bf(h1) << 16);
  }
  if (ck == NCH - 1){ hn[b * 1024 + ch0] = h0; hn[b * 1024 + ch0 + 1] = h1; }
}

// ---------------- launcher ----------------
extern "C" void kernel_launch(void* const* d_in, const int* in_sizes, int n_in,
                              void* d_out, int out_size, void* d_ws, size_t ws_size,
                              hipStream_t stream)
{
  const float* x    = (const float*)d_in[0];
  const void*  isin = d_in[1];
  const float* Whg  = (const float*)d_in[2];
  const float* Wout = (const float*)d_in[3];
  float* out = (float*)d_out;

  char* ws = (char*)d_ws;
  size_t off = 0;
  auto alloc = [&](size_t bytes) -> char* {
    char* p = ws + off;
    off += (bytes + 255) & ~(size_t)255;
    return p;
  };
  u16*   xbf   = (u16*)  alloc((size_t)M_ * DIN * 2);        // 67 MB
  u16*   WThg  = (u16*)  alloc((size_t)2 * HCH * DIN * 2);   // 4 MB
  u16*   WTout = (u16*)  alloc((size_t)DOUT * HCH * 2);      // 2 MB
  u16*   hg    = (u16*)  alloc((size_t)M_ * 2 * HCH * 2);    // 134 MB
  u16*   hbf   = (u16*)  alloc((size_t)M_ * HCH * 2);        // 67 MB
  float* Cc    = (float*)alloc((size_t)NCH * 8192 * 4);      // 2 MB
  float* Vc    = (float*)alloc((size_t)NCH * 8192 * 4);      // 2 MB
  float* hin   = (float*)alloc((size_t)NCH * 8192 * 4);      // 2 MB
  int*   mode  = (int*)  alloc(256);
  (void)ws_size; (void)in_sizes; (void)n_in; (void)out_size;

  prep_kernel<<<11265, 256, 0, stream>>>(x, xbf, Whg, Wout, (const u32*)isin,
                                         WThg, WTout, mode);
  gemm8p_kernel<true, 2048><<<1024, 512, 0, stream>>>(xbf, WThg, hg);
  scanA_kernel<<<(8192*NCH/2)/256, 256, 0, stream>>>(hg, isin, mode, Cc, Vc);
  scanB_kernel<<<8192/256, 256, 0, stream>>>(Cc, Vc, hin);
  scanC_kernel<<<(8192*NCH/2)/256, 256, 0, stream>>>(hg, isin, mode, hin, hbf,
                                                     out + (size_t)M_ * DOUT);
  gemm8p_kernel<false, 1024><<<512, 512, 0, stream>>>(hbf, WTout, out);
}

// Round 10
// 588.198 us; speedup vs baseline: 1.4082x; 1.0424x over previous
//
#include <hip/hip_runtime.h>
#include <stdint.h>

#define B_    8
#define T_    4096
#define DIN   1024
#define HCH   1024
#define DOUT  1024
#define M_    (B_*T_)      // 32768 rows
#define CL    64           // scan chunk length
#define NCH   (T_/CL)      // 64 chunks

typedef unsigned short u16;
typedef unsigned int   u32;
typedef __attribute__((ext_vector_type(8))) __bf16 bf16x8;
typedef __attribute__((ext_vector_type(4))) float  f32x4;
typedef __attribute__((ext_vector_type(2))) unsigned int u32x2;

static __device__ __forceinline__ u16 f2bf(float f){
  unsigned u = __builtin_bit_cast(unsigned, f);
  return (u16)((u + 0x7FFFu + ((u >> 16) & 1u)) >> 16);   // RNE
}
static __device__ __forceinline__ float bf2f(u16 h){
  return __builtin_bit_cast(float, ((unsigned)h) << 16);
}

#define GLOAD_LDS16(gp, lp) __builtin_amdgcn_global_load_lds( \
    (__attribute__((address_space(1))) void*)(gp),            \
    (__attribute__((address_space(3))) void*)(lp), 16, 0, 0)

#define BARRIER() do { __builtin_amdgcn_sched_barrier(0); \
                       __builtin_amdgcn_s_barrier();      \
                       __builtin_amdgcn_sched_barrier(0); } while(0)

// ---------------- prep: x->bf16 cvt + W transposes + is_init detect (1 dispatch) ----------------
static __device__ __forceinline__ void transpose_tile(const float* __restrict__ in,
                                                      u16* __restrict__ out,
                                                      int R, int C, int bx, int by){
  __shared__ float tile[32][33];
  int tx = threadIdx.x & 31, ty = threadIdx.x >> 5;   // 32 x 8
  int c0 = bx * 32, r0 = by * 32;
  #pragma unroll
  for (int j = 0; j < 4; ++j)
    tile[ty + j*8][tx] = in[(size_t)(r0 + ty + j*8) * C + c0 + tx];
  __syncthreads();
  #pragma unroll
  for (int j = 0; j < 4; ++j)
    out[(size_t)(c0 + ty + j*8) * R + r0 + tx] = f2bf(tile[tx][ty + j*8]);
}

__global__ void prep_kernel(const float* __restrict__ x, u16* __restrict__ xbf,
                            const float* __restrict__ Whg, const float* __restrict__ Wout,
                            const u32* __restrict__ isin,
                            u16* __restrict__ WThg, u16* __restrict__ WTout,
                            int* __restrict__ flag){
  int bid = blockIdx.x;
  if (bid < 2048){                       // Whg: [1024][2048] -> WThg [2048][1024]
    transpose_tile(Whg, WThg, DIN, 2*HCH, bid & 63, bid >> 6);
  } else if (bid < 3072){                // Wout: [1024][1024] -> WTout [1024][1024]
    int b2 = bid - 2048;
    transpose_tile(Wout, WTout, HCH, DOUT, b2 & 31, b2 >> 5);
  } else if (bid == 3072){               // detect: 1 => byte-flags, 0 => int32
    __shared__ int s;
    if (threadIdx.x == 0) s = 0;
    __syncthreads();
    int f = 0;
    for (int i = threadIdx.x; i < (B_*T_)/4; i += 256)
      if (isin[i] & 0xFFFFFF00u) f = 1;
    if (f) atomicOr(&s, 1);
    __syncthreads();
    if (threadIdx.x == 0) *flag = s;
  } else {                               // cvt: 8192 blocks x 256 thr x 4 float4
    int cb = bid - 3073;
    #pragma unroll
    for (int k = 0; k < 4; ++k){
      int i = (cb*4 + k)*256 + threadIdx.x;
      float4 v = ((const float4*)x)[i];
      ushort4 o;
      o.x = f2bf(v.x); o.y = f2bf(v.y); o.z = f2bf(v.z); o.w = f2bf(v.w);
      ((ushort4*)xbf)[i] = o;
    }
  }
}

// ---------------- 8-phase 256^2 GEMM, A-locality XCD map, swapped-operand epilogue ----------
// A: [M][1024] bf16.  BT: [NOUT][1024] bf16 (B^T layout).  out: [M][NOUT].
// XCD map: bid = c*(8*NB) + d*8 + x  ->  mb = c*8 + x (unique per XCD), nb = d.
// Each XCD owns a disjoint mb set: A-tiles fetched once into its L2, reused across nb;
// B (<=4MB) is L2-resident. (Round-7 map broadcast each A-tile to all 8 XCDs: FETCH=4x A.)
template<bool BF16OUT, int NOUT>
__global__ __launch_bounds__(512, 2) void gemm8p_kernel(
    const u16* __restrict__ A, const u16* __restrict__ BT, void* __restrict__ outv)
{
  __shared__ u16 As[2][16384];   // [buf][256 rows][64 cols], XOR-swizzled granules
  __shared__ u16 Bs[2][16384];

  const int tid = threadIdx.x, lane = tid & 63, w = tid >> 6;
  const int wm = w >> 2, wn = w & 3;
  const int lr = lane & 15, lg = lane >> 4;
  const int l8 = lane >> 3, l7 = lane & 7;
  const int sgcol = (l7 ^ l8) * 8;             // pre-swizzled source granule

  constexpr int LNB = (NOUT == 2048) ? 3 : 2;  // log2(NOUT/256)
  const int x8 = (int)blockIdx.x & 7;
  const int d8 = ((int)blockIdx.x >> 3) & ((1 << LNB) - 1);
  const int c8 = (int)blockIdx.x >> (3 + LNB);
  const int mb = c8 * 8 + x8;                  // A row-block: unique per XCD
  const int nb = d8;
  const int m0 = mb * 256, n0 = nb * 256;

  const u16* __restrict__ Ab = A  + (size_t)m0 * 1024;
  const u16* __restrict__ Bb = BT + (size_t)n0 * 1024;

  auto stage = [&](u16 (*S)[16384], int buf, int half, int tt, const u16* __restrict__ Gb){
    #pragma unroll
    for (int i = 0; i < 2; ++i){
      int wi = w*2 + i;                        // 1KB window 0..15 within half
      GLOAD_LDS16(Gb + (size_t)(half*128 + wi*8 + l8) * 1024 + tt*64 + sgcol,
                  &S[buf][half*8192 + wi*512]);
    }
  };

  bf16x8 af[4][2], b0[2][2], b1[2][2];
  f32x4 acc[2][2][4][2];
  #pragma unroll
  for (int a = 0; a < 2; ++a)
    #pragma unroll
    for (int b = 0; b < 2; ++b)
      #pragma unroll
      for (int m = 0; m < 4; ++m)
        #pragma unroll
        for (int n = 0; n < 2; ++n)
          acc[a][b][m][n] = (f32x4){0.f,0.f,0.f,0.f};

  auto ldA = [&](int buf, int mh){
    #pragma unroll
    for (int m = 0; m < 4; ++m)
      #pragma unroll
      for (int ks = 0; ks < 2; ++ks){
        int R = mh*128 + wm*64 + m*16 + lr;
        int g = (ks*4 + lg) ^ (lr & 7);
        af[m][ks] = *(const bf16x8*)&As[buf][R*64 + g*8];
      }
  };
  auto ldB = [&](bf16x8 (&bv)[2][2], int buf, int nh){
    #pragma unroll
    for (int n = 0; n < 2; ++n)
      #pragma unroll
      for (int ks = 0; ks < 2; ++ks){
        int R = nh*128 + wn*32 + n*16 + lr;
        int g = (ks*4 + lg) ^ (lr & 7);
        bv[n][ks] = *(const bf16x8*)&Bs[buf][R*64 + g*8];
      }
  };
  auto mmaQ = [&](f32x4 (&ac)[4][2], bf16x8 (&bv)[2][2]){
    __builtin_amdgcn_s_setprio(1);
    #pragma unroll
    for (int m = 0; m < 4; ++m)
      #pragma unroll
      for (int n = 0; n < 2; ++n)
        #pragma unroll
        for (int ks = 0; ks < 2; ++ks)   // SWAPPED operands: D = (A*B)^T fragments
          ac[m][n] = __builtin_amdgcn_mfma_f32_16x16x32_bf16(bv[n][ks], af[m][ks], ac[m][n], 0, 0, 0);
    __builtin_amdgcn_s_setprio(0);
  };

  // ---- prologue: tile0 all 4 halves, tile1 first 3 halves ----
  stage(As, 0, 0, 0, Ab);   // t0.Ah0
  stage(Bs, 0, 0, 0, Bb);   // t0.Bh0
  stage(Bs, 0, 1, 0, Bb);   // t0.Bh1
  stage(As, 0, 1, 0, Ab);   // t0.Ah1
  stage(As, 1, 0, 1, Ab);   // t1.Ah0
  stage(Bs, 1, 0, 1, Bb);   // t1.Bh0
  stage(Bs, 1, 1, 1, Bb);   // t1.Bh1
  asm volatile("s_waitcnt vmcnt(6)" ::: "memory");   // tile0 fully landed
  BARRIER();

  // ---- main loop: 16 K-tiles, 4 phases each (round-3 measured schedule) ----
  for (int t = 0; t < 16; ++t){
    int cur = t & 1;
    // P1 — quadrant (mh0, nh0); stage (t+1).Ah1
    ldA(cur, 0);
    ldB(b0, cur, 0);
    if (t+1 < 16) stage(As, cur^1, 1, t+1, Ab);
    BARRIER();
    mmaQ(acc[0][0], b0);
    BARRIER();
    // P2 — quadrant (mh0, nh1); stage (t+2).Ah0
    ldB(b1, cur, 1);
    if (t+2 < 16) stage(As, cur, 0, t+2, Ab);
    BARRIER();
    mmaQ(acc[0][1], b1);
    BARRIER();
    // P3 — quadrant (mh1, nh1); stage (t+2).Bh0
    ldA(cur, 1);
    if (t+2 < 16) stage(Bs, cur, 0, t+2, Bb);
    BARRIER();
    mmaQ(acc[1][1], b1);
    BARRIER();
    // P4 — quadrant (mh1, nh0); stage (t+2).Bh1; counted vmcnt
    if (t+2 < 16) stage(Bs, cur, 1, t+2, Bb);
    if (t < 14)       { asm volatile("s_waitcnt vmcnt(6)" ::: "memory"); }
    else if (t == 14) { asm volatile("s_waitcnt vmcnt(0)" ::: "memory"); }
    BARRIER();
    mmaQ(acc[1][0], b0);
    BARRIER();
  }

  // ---- epilogue: transposed fragments -> packed row-major stores ----
  #pragma unroll
  for (int mh = 0; mh < 2; ++mh)
    #pragma unroll
    for (int m = 0; m < 4; ++m){
      int row = m0 + mh*128 + wm*64 + m*16 + lr;
      #pragma unroll
      for (int nh = 0; nh < 2; ++nh)
        #pragma unroll
        for (int n = 0; n < 2; ++n){
          int col = n0 + nh*128 + wn*32 + n*16 + lg*4;
          f32x4 v = acc[mh][nh][m][n];
          if (BF16OUT){
            ushort4 p;
            p.x = f2bf(v[0]); p.y = f2bf(v[1]); p.z = f2bf(v[2]); p.w = f2bf(v[3]);
            *(ushort4*)&((u16*)outv)[(size_t)row * NOUT + col] = p;
          } else {
            float4 p = make_float4(v[0], v[1], v[2], v[3]);
            *(float4*)&((float*)outv)[(size_t)row * NOUT + col] = p;
          }
        }
    }
}

// ---------------- fused elementwise: c = sigmoid(-g), v = sigmoid(g)*g_act(h) ----------------
static __device__ __forceinline__ void cv_from_hg(float hv, float gv, float& c, float& v){
  c = 1.f / (1.f + __expf(gv));
  float z = 1.f - c;
  float g = (hv >= 0.f) ? (hv + 0.5f) : (1.f / (1.f + __expf(-hv)));
  v = z * g;
}

// ---------------- chunked scan: 4 channels/thread, 8B loads ----------------
__global__ void scanA_kernel(const u16* __restrict__ hg,
                             const void* __restrict__ isin, const int* __restrict__ mode,
                             float* __restrict__ Cc, float* __restrict__ Vc)
{
  int tid = blockIdx.x * 256 + threadIdx.x;        // 0..131071
  int chp = tid & 255, b = (tid >> 8) & 7, ck = tid >> 11;
  int ch0 = chp * 4;
  int md = *mode;
  const unsigned char* ib = (const unsigned char*)isin;
  const int* ii = (const int*)isin;
  int t0 = b * T_ + ck * CL;
  float C[4] = {1.f,1.f,1.f,1.f}, V[4] = {0.f,0.f,0.f,0.f};
  #pragma unroll 4
  for (int i = 0; i < CL; ++i){
    int t = t0 + i;
    const u16* rowp = hg + (size_t)t * 2048;
    u32x2 h2 = *(const u32x2*)(rowp + ch0);
    u32x2 g2 = *(const u32x2*)(rowp + 1024 + ch0);
    int r = md ? (int)ib[t] : ii[t];
    #pragma unroll
    for (int j = 0; j < 4; ++j){
      float hv = bf2f((u16)(h2[j>>1] >> (16*(j&1))));
      float gv = bf2f((u16)(g2[j>>1] >> (16*(j&1))));
      float c, v;
      cv_from_hg(hv, gv, c, v);
      if (r){ C[j] = 0.f; V[j] = v; }
      else  { V[j] = __fmaf_rn(c, V[j], v); C[j] *= c; }
    }
  }
  int o = ck * 8192 + b * 1024 + ch0;
  *(float4*)&Cc[o] = make_float4(C[0], C[1], C[2], C[3]);
  *(float4*)&Vc[o] = make_float4(V[0], V[1], V[2], V[3]);
}

__global__ void scanB_kernel(const float* __restrict__ Cc, const float* __restrict__ Vc,
                             float* __restrict__ hin)
{
  int idx = blockIdx.x * 256 + threadIdx.x;   // 0..8191
  float h = 0.f;
  #pragma unroll 8
  for (int ck = 0; ck < NCH; ++ck){
    int o = ck * 8192 + idx;
    hin[o] = h;
    h = __fmaf_rn(Cc[o], h, Vc[o]);
  }
}

__global__ void scanC_kernel(const u16* __restrict__ hg,
                             const void* __restrict__ isin, const int* __restrict__ mode,
                             const float* __restrict__ hin,
                             u16* __restrict__ hbf, float* __restrict__ hn)
{
  int tid = blockIdx.x * 256 + threadIdx.x;        // 0..131071
  int chp = tid & 255, b = (tid >> 8) & 7, ck = tid >> 11;
  int ch0 = chp * 4;
  int md = *mode;
  const unsigned char* ib = (const unsigned char*)isin;
  const int* ii = (const int*)isin;
  int t0 = b * T_ + ck * CL;
  int o = ck * 8192 + b * 1024 + ch0;
  float h[4];
  #pragma unroll
  for (int j = 0; j < 4; ++j) h[j] = hin[o + j];
  #pragma unroll 4
  for (int i = 0; i < CL; ++i){
    int t = t0 + i;
    const u16* rowp = hg + (size_t)t * 2048;
    u32x2 h2 = *(const u32x2*)(rowp + ch0);
    u32x2 g2 = *(const u32x2*)(rowp + 1024 + ch0);
    int r = md ? (int)ib[t] : ii[t];
    u32x2 w;
    #pragma unroll
    for (int j = 0; j < 4; ++j){
      float hv = bf2f((u16)(h2[j>>1] >> (16*(j&1))));
      float gv = bf2f((u16)(g2[j>>1] >> (16*(j&1))));
      float c, v;
      cv_from_hg(hv, gv, c, v);
      h[j] = r ? v : __fmaf_rn(c, h[j], v);
      u32 bits = (u32)f2bf(h[j]);
      if ((j & 1) == 0) w[j>>1] = bits;
      else              w[j>>1] |= bits << 16;
    }
    *(u32x2*)&hbf[(size_t)t * HCH + ch0] = w;
  }
  if (ck == NCH - 1){
    #pragma unroll
    for (int j = 0; j < 4; ++j) hn[b * 1024 + ch0 + j] = h[j];
  }
}

// ---------------- launcher ----------------
extern "C" void kernel_launch(void* const* d_in, const int* in_sizes, int n_in,
                              void* d_out, int out_size, void* d_ws, size_t ws_size,
                              hipStream_t stream)
{
  const float* x    = (const float*)d_in[0];
  const void*  isin = d_in[1];
  const float* Whg  = (const float*)d_in[2];
  const float* Wout = (const float*)d_in[3];
  float* out = (float*)d_out;

  char* ws = (char*)d_ws;
  size_t off = 0;
  auto alloc = [&](size_t bytes) -> char* {
    char* p = ws + off;
    off += (bytes + 255) & ~(size_t)255;
    return p;
  };
  u16*   xbf   = (u16*)  alloc((size_t)M_ * DIN * 2);        // 67 MB
  u16*   WThg  = (u16*)  alloc((size_t)2 * HCH * DIN * 2);   // 4 MB
  u16*   WTout = (u16*)  alloc((size_t)DOUT * HCH * 2);      // 2 MB
  u16*   hg    = (u16*)  alloc((size_t)M_ * 2 * HCH * 2);    // 134 MB
  u16*   hbf   = (u16*)  alloc((size_t)M_ * HCH * 2);        // 67 MB
  float* Cc    = (float*)alloc((size_t)NCH * 8192 * 4);      // 2 MB
  float* Vc    = (float*)alloc((size_t)NCH * 8192 * 4);      // 2 MB
  float* hin   = (float*)alloc((size_t)NCH * 8192 * 4);      // 2 MB
  int*   mode  = (int*)  alloc(256);
  (void)ws_size; (void)in_sizes; (void)n_in; (void)out_size;

  prep_kernel<<<11265, 256, 0, stream>>>(x, xbf, Whg, Wout, (const u32*)isin,
                                         WThg, WTout, mode);
  gemm8p_kernel<true, 2048><<<1024, 512, 0, stream>>>(xbf, WThg, hg);
  scanA_kernel<<<512, 256, 0, stream>>>(hg, isin, mode, Cc, Vc);
  scanB_kernel<<<8192/256, 256, 0, stream>>>(Cc, Vc, hin);
  scanC_kernel<<<512, 256, 0, stream>>>(hg, isin, mode, hin, hbf,
                                        out + (size_t)M_ * DOUT);
  gemm8p_kernel<false, 1024><<<512, 512, 0, stream>>>(hbf, WTout, out);
}